// Round 11
// baseline (97.482 us; speedup 1.0000x reference)
//
#include <hip/hip_runtime.h>
#include <hip/hip_bf16.h>

// DendriticLayerSiLU: out = silu(softmax-gated template proj) * (x @ W^T)
// N=4096 tokens, K=2048, H=1024, 32 windows of 64.
// Round 11: r10 + MFMA shape 32x32x16 (half the instructions, ~17% fewer
// matrix-pipe cycles; layouts validated end-to-end in r5, bank pattern
// conflict-free under the r9 chunk^(row&7) swizzle). Everything else frozen:
// BK=64 window==K-step, 160 KB dbuf, one barrier per K=64, raw v_exp_f32
// gate with log2e folded into T prepass, setprio around MFMA clusters.

typedef __attribute__((ext_vector_type(8))) short short8;
typedef __attribute__((ext_vector_type(4))) float f32x4;
typedef __attribute__((ext_vector_type(16))) float f32x16;

#define N_TOK 4096
#define K_DIM 2048
#define H_DIM 1024
#define BM 128
#define BH 128
#define BK 64
#define LDSZ (BM * BK)            // 8192 shorts = 16 KB per array

#define X_ELEMS (N_TOK * K_DIM)   // 8388608
#define W_ELEMS (H_DIM * K_DIM)   // 2097152
#define WS_NEED ((size_t)(2 * X_ELEMS + 3 * W_ELEMS) * 2)  // 46,137,344 B

#define XB (X_ELEMS / 8 / 256)    // 4096 prepass blocks for X
#define WB (W_ELEMS / 8 / 256)    // 1024 for W, 1024 for T

#define LOG2E 1.4426950408889634f
#define LN2   0.6931471805599453f

// raw v_exp_f32 (computes 2^x, ~1 ULP) — 1 instruction, fabs folds free.
#if defined(__has_builtin)
#if __has_builtin(__builtin_amdgcn_exp2f)
#define EXP2RAW(x) __builtin_amdgcn_exp2f(x)
#endif
#endif
#ifndef EXP2RAW
__device__ __forceinline__ float exp2raw_asm(float x) {
    float r;
    asm("v_exp_f32 %0, %1" : "=v"(r) : "v"(x));
    return r;
}
#define EXP2RAW(x) exp2raw_asm(x)
#endif

__device__ __forceinline__ unsigned short f2bf(float f) {
    unsigned int u = __float_as_uint(f);
    u += 0x7FFFu + ((u >> 16) & 1u);    // round-to-nearest-even
    return (unsigned short)(u >> 16);
}
__device__ __forceinline__ float bf2f(unsigned short h) {
    return __uint_as_float(((unsigned int)h) << 16);
}

__device__ __forceinline__ void cvt_split(f32x4 a, f32x4 b, short8& vh, short8& vl) {
#pragma unroll
    for (int i = 0; i < 4; ++i) {
        float f = a[i];
        unsigned short h = f2bf(f);
        vh[i] = (short)h;
        vl[i] = (short)f2bf(f - bf2f(h));
    }
#pragma unroll
    for (int i = 0; i < 4; ++i) {
        float f = b[i];
        unsigned short h = f2bf(f);
        vh[i + 4] = (short)h;
        vl[i + 4] = (short)f2bf(f - bf2f(h));
    }
}
__device__ __forceinline__ short8 cvt_hi(f32x4 a, f32x4 b) {
    short8 v;
#pragma unroll
    for (int i = 0; i < 4; ++i) { v[i] = (short)f2bf(a[i]); v[i + 4] = (short)f2bf(b[i]); }
    return v;
}

#define MFMA32(A, B, C) __builtin_amdgcn_mfma_f32_32x32x16_bf16(A, B, C, 0, 0, 0)

// ---------------------------------------------------------------- prepass ---
// X,W -> hi/lo bf16 split; T -> bf16 scaled by log2e (exp2-based softmax).
__global__ __launch_bounds__(256) void prepass_all(
    const float* __restrict__ X, const float* __restrict__ W,
    const float* __restrict__ T,
    unsigned short* __restrict__ XH, unsigned short* __restrict__ XL,
    unsigned short* __restrict__ WH, unsigned short* __restrict__ WL,
    unsigned short* __restrict__ TH)
{
    int b = blockIdx.x;
    if (b < XB + WB) {
        const float* src; unsigned short *hi, *lo; int i;
        if (b < XB) { src = X; hi = XH; lo = XL; i = b * 256 + threadIdx.x; }
        else        { src = W; hi = WH; lo = WL; i = (b - XB) * 256 + threadIdx.x; }
        const float* p = src + (size_t)i * 8;
        f32x4 a = *(const f32x4*)p;
        f32x4 c = *(const f32x4*)(p + 4);
        short8 vh, vl;
        cvt_split(a, c, vh, vl);
        *(short8*)&hi[(size_t)i * 8] = vh;
        *(short8*)&lo[(size_t)i * 8] = vl;
    } else {
        int i = (b - XB - WB) * 256 + threadIdx.x;
        const float* p = T + (size_t)i * 8;
        f32x4 a = *(const f32x4*)p;
        f32x4 c = *(const f32x4*)(p + 4);
#pragma unroll
        for (int j = 0; j < 4; ++j) { a[j] *= LOG2E; c[j] *= LOG2E; }
        *(short8*)&TH[(size_t)i * 8] = cvt_hi(a, c);
    }
}

// ------------------------------------------------------------- main GEMM ----
#define GLL(gp, lp) __builtin_amdgcn_global_load_lds(                      \
        (const __attribute__((address_space(1))) void*)(gp),               \
        (__attribute__((address_space(3))) void*)(lp), 16, 0, 0)

__global__ __launch_bounds__(512) void dend_gemm(
    const unsigned short* __restrict__ XH, const unsigned short* __restrict__ XL,
    const unsigned short* __restrict__ WH, const unsigned short* __restrict__ WL,
    const unsigned short* __restrict__ TH, float* __restrict__ O)
{
    // arrays: 0=x_hi 1=x_lo 2=w_hi 3=w_lo 4=t_hi ; [128][64] shorts each;
    // double-buffered -> 160 KB (full CU LDS, 1 block/CU by design).
    __shared__ __align__(16) short lds[2][5][LDSZ];

    const int tid  = threadIdx.x;
    const int lane = tid & 63;
    const int wv   = tid >> 6;    // 0..7
    const int wm   = wv >> 2;     // 0..1  (64 token-rows each, 2 x 32-frags)
    const int wn   = wv & 3;      // 0..3  (one 32-col frag each)

    const int bid     = blockIdx.x;
    const int logical = (bid & 7) * 32 + (bid >> 3);   // XCD-chunked swizzle
    const int hb   = logical >> 5;   // 0..7
    const int nb   = logical & 31;   // 0..31
    const int row0 = nb * BM;
    const int col0 = hb * BH;

    // ---- staging (frozen from r9/r10): row = 64 shorts = 8 chunks of 16B.
    //   content(row, slot) = logical chunk  slot ^ (row & 7).
    // GLL (1 KB linear): lane l -> row +(l>>3), slot l&7  =>
    //   source chunk = (l&7) ^ (l>>3).  Two GLLs per 16-row wave stripe.
    const int srow8 = lane >> 3;                 // 0..7
    const int schk  = (lane & 7) ^ srow8;        // pre-swizzled source chunk
    const size_t xbase = (size_t)(row0 + wv * 16 + srow8) * K_DIM + schk * 8;
    const size_t wbase = (size_t)(col0 + wv * 16 + srow8) * K_DIM + schk * 8;
    const size_t rstep8 = (size_t)8 * K_DIM;     // +8 rows
    const int dst0 = (wv * 16) * BK;             // short index of stripe row 0
    const int dst1 = dst0 + 8 * BK;

#define STAGE(buf, t) do {                                                 \
        const size_t ko = (size_t)(t) * BK;                                \
        GLL(XH + xbase + ko,          &lds[buf][0][dst0]);                 \
        GLL(XH + xbase + rstep8 + ko, &lds[buf][0][dst1]);                 \
        GLL(XL + xbase + ko,          &lds[buf][1][dst0]);                 \
        GLL(XL + xbase + rstep8 + ko, &lds[buf][1][dst1]);                 \
        GLL(WH + wbase + ko,          &lds[buf][2][dst0]);                 \
        GLL(WH + wbase + rstep8 + ko, &lds[buf][2][dst1]);                 \
        GLL(WL + wbase + ko,          &lds[buf][3][dst0]);                 \
        GLL(WL + wbase + rstep8 + ko, &lds[buf][3][dst1]);                 \
        GLL(TH + wbase + ko,          &lds[buf][4][dst0]);                 \
        GLL(TH + wbase + rstep8 + ko, &lds[buf][4][dst1]);                 \
    } while (0)

    // ---- 32x32x16 fragment read offsets. A/B operand: lane L holds row
    // L&31, k = (L>>5)*8 + i (validated end-to-end in r5). Logical chunk
    // for K-slice kc (K=16) = kc*2 + (lane>>5); slot = chunk ^ (row&7).
    // Bank check: lanes 0-15 -> rows 0-15 -> slots c^0..c^7 twice (the
    // exact pattern r9/r10 measured at 0 conflicts); lanes 16-31 repeat.
    int a_off[2][4], b_off[4];
#pragma unroll
    for (int mi = 0; mi < 2; ++mi) {
        int r = wm * 64 + mi * 32 + (lane & 31);
#pragma unroll
        for (int kc = 0; kc < 4; ++kc)
            a_off[mi][kc] = r * BK + ((kc * 2 + (lane >> 5)) ^ (r & 7)) * 8;
    }
    {
        int r = wn * 32 + (lane & 31);
#pragma unroll
        for (int kc = 0; kc < 4; ++kc)
            b_off[kc] = r * BK + ((kc * 2 + (lane >> 5)) ^ (r & 7)) * 8;
    }

    const f32x16 zeroc = (f32x16)0.0f;
    f32x16 lin[2], num[2], den[2], win[2];
#pragma unroll
    for (int mi = 0; mi < 2; ++mi) {
        lin[mi] = zeroc; num[mi] = zeroc; den[mi] = zeroc;
    }

    // One K-step = one window: 4 K-slices of 32x32x16 MFMA (setprio-wrapped),
    // then inline EPILOG on the completed win. e = v_exp_f32(|d|) = exp(|a|)
    // since T carries log2e from the prepass.
#define COMP_EPI(buf) do {                                                 \
        _Pragma("unroll")                                                  \
        for (int kc = 0; kc < 4; ++kc) {                                   \
            short8 bwh = *(const short8*)&lds[buf][2][b_off[kc]];          \
            short8 bwl = *(const short8*)&lds[buf][3][b_off[kc]];          \
            short8 bth = *(const short8*)&lds[buf][4][b_off[kc]];          \
            __builtin_amdgcn_s_setprio(1);                                 \
            _Pragma("unroll")                                              \
            for (int mi = 0; mi < 2; ++mi) {                               \
                short8 ah = *(const short8*)&lds[buf][0][a_off[mi][kc]];   \
                short8 al = *(const short8*)&lds[buf][1][a_off[mi][kc]];   \
                lin[mi] = MFMA32(ah, bwh, lin[mi]);                        \
                lin[mi] = MFMA32(al, bwh, lin[mi]);                        \
                lin[mi] = MFMA32(ah, bwl, lin[mi]);                        \
                win[mi] = MFMA32(ah, bth, (kc == 0) ? zeroc : win[mi]);    \
            }                                                              \
            __builtin_amdgcn_s_setprio(0);                                 \
        }                                                                  \
        _Pragma("unroll")                                                  \
        for (int mi = 0; mi < 2; ++mi)                                     \
        _Pragma("unroll")                                                  \
        for (int i = 0; i < 16; ++i) {                                     \
            float d = win[mi][i];                                          \
            float e = EXP2RAW(fabsf(d));                                   \
            den[mi][i] += e;                                               \
            num[mi][i] = fmaf(e, d, num[mi][i]);                           \
        }                                                                  \
    } while (0)

    STAGE(0, 0);
    __syncthreads();

    // One barrier per K=64 step (frozen r9 structure).
#pragma unroll 1
    for (int w = 0; w < 16; ++w) {
        const int t0 = 2 * w;
        STAGE(1, t0 + 1);
        COMP_EPI(0);
        __syncthreads();
        if (t0 + 2 < 32) STAGE(0, t0 + 2);
        COMP_EPI(1);
        __syncthreads();
    }

    // Final epilogue. C/D 32x32: col = lane&31, row = (i&3)+8*(i>>2)+4*(lane>>5)
#pragma unroll
    for (int mi = 0; mi < 2; ++mi)
#pragma unroll
        for (int i = 0; i < 16; ++i) {
            float gg   = (num[mi][i] / den[mi][i]) * LN2;
            float gate = gg / (1.0f + __expf(-gg));
            float val  = gate * lin[mi][i];
            int r = row0 + wm * 64 + mi * 32 + (i & 3) + 8 * (i >> 2) + 4 * (lane >> 5);
            int c = col0 + wn * 32 + (lane & 31);
            O[(size_t)r * H_DIM + c] = val;
        }
#undef STAGE
#undef COMP_EPI
}

// ------------------------------------------------- fallback (round-1 path) --
#define MFMA16(A, B, C) __builtin_amdgcn_mfma_f32_16x16x32_bf16(A, B, C, 0, 0, 0)

__global__ __launch_bounds__(512) void dend_fused_v0(
    const float* __restrict__ X, const float* __restrict__ T,
    const float* __restrict__ W, float* __restrict__ O)
{
    __shared__ __align__(16) short lds[2][5][128 * 32];

    const int tid  = threadIdx.x;
    const int lane = tid & 63;
    const int wv   = tid >> 6;
    const int wm   = wv >> 2;
    const int wn   = wv & 3;

    const int bid     = blockIdx.x;
    const int logical = (bid & 7) * 32 + (bid >> 3);
    const int hb   = logical >> 5;
    const int nb   = logical & 31;
    const int row0 = nb * 128;
    const int col0 = hb * 128;

    const int srow  = tid >> 2;
    const int schn  = tid & 3;
    const int sslot = schn ^ ((srow >> 1) & 3);
    const int swoff = srow * 32 + sslot * 8;

    const float* gx = X + (size_t)(row0 + srow) * K_DIM + schn * 8;
    const float* gw = W + (size_t)(col0 + srow) * K_DIM + schn * 8;
    const float* gt = T + (size_t)(col0 + srow) * K_DIM + schn * 8;

    const int g = lane >> 4;
    int a_off[4], b_off[2];
#pragma unroll
    for (int mi = 0; mi < 4; ++mi) {
        int r = wm * 64 + mi * 16 + (lane & 15);
        a_off[mi] = r * 32 + (g ^ ((r >> 1) & 3)) * 8;
    }
#pragma unroll
    for (int nj = 0; nj < 2; ++nj) {
        int r = wn * 32 + nj * 16 + (lane & 15);
        b_off[nj] = r * 32 + (g ^ ((r >> 1) & 3)) * 8;
    }

    const f32x4 zeroc = (f32x4)0.0f;
    f32x4 lin[4][2], num[4][2], den[4][2], win[4][2];
#pragma unroll
    for (int mi = 0; mi < 4; ++mi)
#pragma unroll
        for (int nj = 0; nj < 2; ++nj) {
            lin[mi][nj] = zeroc; num[mi][nj] = zeroc; den[mi][nj] = zeroc;
        }

    f32x4 rx0, rx1, rw0, rw1, rt0, rt1;

#define LOADS(t) do {                                                   \
        const float* px = gx + (size_t)(t) * 32;                        \
        const float* pw = gw + (size_t)(t) * 32;                        \
        const float* pt = gt + (size_t)(t) * 32;                        \
        rx0 = *(const f32x4*)(px); rx1 = *(const f32x4*)(px + 4);       \
        rw0 = *(const f32x4*)(pw); rw1 = *(const f32x4*)(pw + 4);       \
        rt0 = *(const f32x4*)(pt); rt1 = *(const f32x4*)(pt + 4);       \
    } while (0)

#define WRITE(buf) do {                                                 \
        short8 vh, vl;                                                  \
        cvt_split(rx0, rx1, vh, vl);                                    \
        *(short8*)&lds[buf][0][swoff] = vh;                             \
        *(short8*)&lds[buf][1][swoff] = vl;                             \
        cvt_split(rw0, rw1, vh, vl);                                    \
        *(short8*)&lds[buf][2][swoff] = vh;                             \
        *(short8*)&lds[buf][3][swoff] = vl;                             \
        *(short8*)&lds[buf][4][swoff] = cvt_hi(rt0, rt1);               \
    } while (0)

#define COMPUTE(buf, ZW) do {                                           \
        short8 bwh[2], bwl[2], bth[2];                                  \
        _Pragma("unroll")                                               \
        for (int nj = 0; nj < 2; ++nj) {                                \
            bwh[nj] = *(const short8*)&lds[buf][2][b_off[nj]];          \
            bwl[nj] = *(const short8*)&lds[buf][3][b_off[nj]];          \
            bth[nj] = *(const short8*)&lds[buf][4][b_off[nj]];          \
        }                                                               \
        _Pragma("unroll")                                               \
        for (int mi = 0; mi < 4; ++mi) {                                \
            short8 ah = *(const short8*)&lds[buf][0][a_off[mi]];        \
            short8 al = *(const short8*)&lds[buf][1][a_off[mi]];        \
            _Pragma("unroll")                                           \
            for (int nj = 0; nj < 2; ++nj) {                            \
                lin[mi][nj] = MFMA16(ah, bwh[nj], lin[mi][nj]);         \
                lin[mi][nj] = MFMA16(al, bwh[nj], lin[mi][nj]);         \
                lin[mi][nj] = MFMA16(ah, bwl[nj], lin[mi][nj]);         \
                win[mi][nj] = MFMA16(ah, bth[nj], (ZW) ? zeroc : win[mi][nj]); \
            }                                                           \
        }                                                               \
    } while (0)

#define EPILOG() do {                                                   \
        _Pragma("unroll")                                               \
        for (int mi = 0; mi < 4; ++mi)                                  \
        _Pragma("unroll")                                               \
        for (int nj = 0; nj < 2; ++nj)                                  \
        _Pragma("unroll")                                               \
        for (int i = 0; i < 4; ++i) {                                   \
            float d = win[mi][nj][i];                                   \
            float e = __expf(fabsf(d));                                 \
            den[mi][nj][i] += e;                                        \
            num[mi][nj][i] = fmaf(e, d, num[mi][nj][i]);                \
        }                                                               \
    } while (0)

    LOADS(0);
    WRITE(0);
    __syncthreads();

#pragma unroll 1
    for (int w = 0; w < 32; ++w) {
        const int t0 = 2 * w;
        LOADS(t0 + 1);
        COMPUTE(0, true);
        __syncthreads();
        WRITE(1);
        __syncthreads();
        const bool more = (w < 31);
        if (more) LOADS(t0 + 2);
        COMPUTE(1, false);
        EPILOG();
        __syncthreads();
        if (more) WRITE(0);
        __syncthreads();
    }

#pragma unroll
    for (int mi = 0; mi < 4; ++mi)
#pragma unroll
        for (int nj = 0; nj < 2; ++nj)
#pragma unroll
            for (int i = 0; i < 4; ++i) {
                float gg   = num[mi][nj][i] / den[mi][nj][i];
                float gate = gg / (1.0f + __expf(-gg));
                float val  = gate * lin[mi][nj][i];
                int r = row0 + wm * 64 + mi * 16 + (lane >> 4) * 4 + i;
                int c = col0 + wn * 32 + nj * 16 + (lane & 15);
                O[(size_t)r * H_DIM + c] = val;
            }
#undef LOADS
#undef WRITE
#undef COMPUTE
#undef EPILOG
}

extern "C" void kernel_launch(void* const* d_in, const int* in_sizes, int n_in,
                              void* d_out, int out_size, void* d_ws, size_t ws_size,
                              hipStream_t stream) {
    const float* X = (const float*)d_in[0];   // x [4096,2048]
    const float* T = (const float*)d_in[1];   // template_flat [1024,2048]
    const float* W = (const float*)d_in[2];   // weights [1024,2048]
    float* O = (float*)d_out;                 // [4096,1024]
    (void)in_sizes; (void)n_in; (void)out_size;

    if (ws_size >= WS_NEED) {
        unsigned short* XHp = (unsigned short*)d_ws;
        unsigned short* XLp = XHp + X_ELEMS;
        unsigned short* WHp = XLp + X_ELEMS;
        unsigned short* WLp = WHp + W_ELEMS;
        unsigned short* THp = WLp + W_ELEMS;
        prepass_all<<<XB + 2 * WB, 256, 0, stream>>>(X, W, T, XHp, XLp, WHp, WLp, THp);
        dend_gemm<<<256, 512, 0, stream>>>(XHp, XLp, WHp, WLp, THp, O);
    } else {
        dend_fused_v0<<<256, 512, 0, stream>>>(X, T, W, O);
    }
}

// Round 12
// 96.125 us; speedup vs baseline: 1.0141x; 1.0141x over previous
//
#include <hip/hip_runtime.h>
#include <hip/hip_bf16.h>

// DendriticLayerSiLU: out = silu(softmax-gated template proj) * (x @ W^T)
// N=4096 tokens, K=2048, H=1024, 32 windows of 64.
// Round 12: r11 (32x32x16 MFMA, BK=64, 160 KB dbuf, one barrier/K-step,
// raw v_exp_f32 gate, setprio) + upgraded swizzle
//   slot = chunk ^ (r&7) ^ (((r>>3)&3)<<1)
// fixing the 4-way conflict r11 measured (7.34e6): interleaved-lane service
// groups share chunk AND r&7 for rows r,r+8,r+16,r+24 under the old swizzle.
// Staging source pre-swizzle carries the same involution (rule: both sides).

typedef __attribute__((ext_vector_type(8))) short short8;
typedef __attribute__((ext_vector_type(4))) float f32x4;
typedef __attribute__((ext_vector_type(16))) float f32x16;

#define N_TOK 4096
#define K_DIM 2048
#define H_DIM 1024
#define BM 128
#define BH 128
#define BK 64
#define LDSZ (BM * BK)            // 8192 shorts = 16 KB per array

#define X_ELEMS (N_TOK * K_DIM)   // 8388608
#define W_ELEMS (H_DIM * K_DIM)   // 2097152
#define WS_NEED ((size_t)(2 * X_ELEMS + 3 * W_ELEMS) * 2)  // 46,137,344 B

#define XB (X_ELEMS / 8 / 256)    // 4096 prepass blocks for X
#define WB (W_ELEMS / 8 / 256)    // 1024 for W, 1024 for T

#define LOG2E 1.4426950408889634f
#define LN2   0.6931471805599453f

// raw v_exp_f32 (computes 2^x, ~1 ULP) — 1 instruction, fabs folds free.
#if defined(__has_builtin)
#if __has_builtin(__builtin_amdgcn_exp2f)
#define EXP2RAW(x) __builtin_amdgcn_exp2f(x)
#endif
#endif
#ifndef EXP2RAW
__device__ __forceinline__ float exp2raw_asm(float x) {
    float r;
    asm("v_exp_f32 %0, %1" : "=v"(r) : "v"(x));
    return r;
}
#define EXP2RAW(x) exp2raw_asm(x)
#endif

__device__ __forceinline__ unsigned short f2bf(float f) {
    unsigned int u = __float_as_uint(f);
    u += 0x7FFFu + ((u >> 16) & 1u);    // round-to-nearest-even
    return (unsigned short)(u >> 16);
}
__device__ __forceinline__ float bf2f(unsigned short h) {
    return __uint_as_float(((unsigned int)h) << 16);
}

__device__ __forceinline__ void cvt_split(f32x4 a, f32x4 b, short8& vh, short8& vl) {
#pragma unroll
    for (int i = 0; i < 4; ++i) {
        float f = a[i];
        unsigned short h = f2bf(f);
        vh[i] = (short)h;
        vl[i] = (short)f2bf(f - bf2f(h));
    }
#pragma unroll
    for (int i = 0; i < 4; ++i) {
        float f = b[i];
        unsigned short h = f2bf(f);
        vh[i + 4] = (short)h;
        vl[i + 4] = (short)f2bf(f - bf2f(h));
    }
}
__device__ __forceinline__ short8 cvt_hi(f32x4 a, f32x4 b) {
    short8 v;
#pragma unroll
    for (int i = 0; i < 4; ++i) { v[i] = (short)f2bf(a[i]); v[i + 4] = (short)f2bf(b[i]); }
    return v;
}

#define MFMA32(A, B, C) __builtin_amdgcn_mfma_f32_32x32x16_bf16(A, B, C, 0, 0, 0)

// ---------------------------------------------------------------- prepass ---
// X,W -> hi/lo bf16 split; T -> bf16 scaled by log2e (exp2-based softmax).
__global__ __launch_bounds__(256) void prepass_all(
    const float* __restrict__ X, const float* __restrict__ W,
    const float* __restrict__ T,
    unsigned short* __restrict__ XH, unsigned short* __restrict__ XL,
    unsigned short* __restrict__ WH, unsigned short* __restrict__ WL,
    unsigned short* __restrict__ TH)
{
    int b = blockIdx.x;
    if (b < XB + WB) {
        const float* src; unsigned short *hi, *lo; int i;
        if (b < XB) { src = X; hi = XH; lo = XL; i = b * 256 + threadIdx.x; }
        else        { src = W; hi = WH; lo = WL; i = (b - XB) * 256 + threadIdx.x; }
        const float* p = src + (size_t)i * 8;
        f32x4 a = *(const f32x4*)p;
        f32x4 c = *(const f32x4*)(p + 4);
        short8 vh, vl;
        cvt_split(a, c, vh, vl);
        *(short8*)&hi[(size_t)i * 8] = vh;
        *(short8*)&lo[(size_t)i * 8] = vl;
    } else {
        int i = (b - XB - WB) * 256 + threadIdx.x;
        const float* p = T + (size_t)i * 8;
        f32x4 a = *(const f32x4*)p;
        f32x4 c = *(const f32x4*)(p + 4);
#pragma unroll
        for (int j = 0; j < 4; ++j) { a[j] *= LOG2E; c[j] *= LOG2E; }
        *(short8*)&TH[(size_t)i * 8] = cvt_hi(a, c);
    }
}

// ------------------------------------------------------------- main GEMM ----
#define GLL(gp, lp) __builtin_amdgcn_global_load_lds(                      \
        (const __attribute__((address_space(1))) void*)(gp),               \
        (__attribute__((address_space(3))) void*)(lp), 16, 0, 0)

__global__ __launch_bounds__(512) void dend_gemm(
    const unsigned short* __restrict__ XH, const unsigned short* __restrict__ XL,
    const unsigned short* __restrict__ WH, const unsigned short* __restrict__ WL,
    const unsigned short* __restrict__ TH, float* __restrict__ O)
{
    // arrays: 0=x_hi 1=x_lo 2=w_hi 3=w_lo 4=t_hi ; [128][64] shorts each;
    // double-buffered -> 160 KB (full CU LDS, 1 block/CU by design).
    __shared__ __align__(16) short lds[2][5][LDSZ];

    const int tid  = threadIdx.x;
    const int lane = tid & 63;
    const int wv   = tid >> 6;    // 0..7
    const int wm   = wv >> 2;     // 0..1  (64 token-rows each, 2 x 32-frags)
    const int wn   = wv & 3;      // 0..3  (one 32-col frag each)

    const int bid     = blockIdx.x;
    const int logical = (bid & 7) * 32 + (bid >> 3);   // XCD-chunked swizzle
    const int hb   = logical >> 5;   // 0..7
    const int nb   = logical & 31;   // 0..31
    const int row0 = nb * BM;
    const int col0 = hb * BH;

    // ---- staging. LDS layout: content(row, slot) = logical chunk
    //   slot ^ (row&7) ^ (((row>>3)&3)<<1).
    // GLL (1 KB linear): lane l -> row R0 + (l>>3), slot l&7. For stripe s
    // of wave wv, (row>>3)&3 = (2*wv + s) & 3, row&7 = l>>3. So the global
    // source chunk = (l&7) ^ (l>>3) ^ (((2*wv+s)&3)<<1).
    const int srow8 = lane >> 3;                 // 0..7
    const int sb0   = (lane & 7) ^ srow8;
    const int schk0 = sb0 ^ (((wv * 2)     & 3) << 1);
    const int schk1 = sb0 ^ (((wv * 2 + 1) & 3) << 1);
    const size_t xbase0 = (size_t)(row0 + wv * 16 +     srow8) * K_DIM + schk0 * 8;
    const size_t xbase1 = (size_t)(row0 + wv * 16 + 8 + srow8) * K_DIM + schk1 * 8;
    const size_t wbase0 = (size_t)(col0 + wv * 16 +     srow8) * K_DIM + schk0 * 8;
    const size_t wbase1 = (size_t)(col0 + wv * 16 + 8 + srow8) * K_DIM + schk1 * 8;
    const int dst0 = (wv * 16) * BK;             // short index of stripe row 0
    const int dst1 = dst0 + 8 * BK;

#define STAGE(buf, t) do {                                                 \
        const size_t ko = (size_t)(t) * BK;                                \
        GLL(XH + xbase0 + ko, &lds[buf][0][dst0]);                         \
        GLL(XH + xbase1 + ko, &lds[buf][0][dst1]);                         \
        GLL(XL + xbase0 + ko, &lds[buf][1][dst0]);                         \
        GLL(XL + xbase1 + ko, &lds[buf][1][dst1]);                         \
        GLL(WH + wbase0 + ko, &lds[buf][2][dst0]);                         \
        GLL(WH + wbase1 + ko, &lds[buf][2][dst1]);                         \
        GLL(WL + wbase0 + ko, &lds[buf][3][dst0]);                         \
        GLL(WL + wbase1 + ko, &lds[buf][3][dst1]);                         \
        GLL(TH + wbase0 + ko, &lds[buf][4][dst0]);                         \
        GLL(TH + wbase1 + ko, &lds[buf][4][dst1]);                         \
    } while (0)

    // ---- 32x32x16 fragment read offsets. Lane L: row L&31, k=(L>>5)*8+i.
    // Logical chunk for K-slice kc = kc*2 + (lane>>5);
    // slot = chunk ^ (r&7) ^ (((r>>3)&3)<<1).
    // Conflict check, contiguous-8 service: rows r..r+7 share r>>3 -> slots
    // c^0..c^7 distinct. Interleaved-8 service: rows r,r+8,r+16,r+24 ->
    // XOR 0,2,4,6 distinct; other chunk half fills odd slots -> all 8.
    int a_off[2][4], b_off[4];
#pragma unroll
    for (int mi = 0; mi < 2; ++mi) {
        int r = wm * 64 + mi * 32 + (lane & 31);
#pragma unroll
        for (int kc = 0; kc < 4; ++kc)
            a_off[mi][kc] = r * BK +
                (((kc * 2 + (lane >> 5)) ^ (r & 7) ^ (((r >> 3) & 3) << 1)) * 8);
    }
    {
        int r = wn * 32 + (lane & 31);
#pragma unroll
        for (int kc = 0; kc < 4; ++kc)
            b_off[kc] = r * BK +
                (((kc * 2 + (lane >> 5)) ^ (r & 7) ^ (((r >> 3) & 3) << 1)) * 8);
    }

    const f32x16 zeroc = (f32x16)0.0f;
    f32x16 lin[2], num[2], den[2], win[2];
#pragma unroll
    for (int mi = 0; mi < 2; ++mi) {
        lin[mi] = zeroc; num[mi] = zeroc; den[mi] = zeroc;
    }

    // One K-step = one window: 4 K-slices of 32x32x16 MFMA (setprio-wrapped),
    // then inline EPILOG on the completed win. e = v_exp_f32(|d|) = exp(|a|)
    // since T carries log2e from the prepass.
#define COMP_EPI(buf) do {                                                 \
        _Pragma("unroll")                                                  \
        for (int kc = 0; kc < 4; ++kc) {                                   \
            short8 bwh = *(const short8*)&lds[buf][2][b_off[kc]];          \
            short8 bwl = *(const short8*)&lds[buf][3][b_off[kc]];          \
            short8 bth = *(const short8*)&lds[buf][4][b_off[kc]];          \
            __builtin_amdgcn_s_setprio(1);                                 \
            _Pragma("unroll")                                              \
            for (int mi = 0; mi < 2; ++mi) {                               \
                short8 ah = *(const short8*)&lds[buf][0][a_off[mi][kc]];   \
                short8 al = *(const short8*)&lds[buf][1][a_off[mi][kc]];   \
                lin[mi] = MFMA32(ah, bwh, lin[mi]);                        \
                lin[mi] = MFMA32(al, bwh, lin[mi]);                        \
                lin[mi] = MFMA32(ah, bwl, lin[mi]);                        \
                win[mi] = MFMA32(ah, bth, (kc == 0) ? zeroc : win[mi]);    \
            }                                                              \
            __builtin_amdgcn_s_setprio(0);                                 \
        }                                                                  \
        _Pragma("unroll")                                                  \
        for (int mi = 0; mi < 2; ++mi)                                     \
        _Pragma("unroll")                                                  \
        for (int i = 0; i < 16; ++i) {                                     \
            float d = win[mi][i];                                          \
            float e = EXP2RAW(fabsf(d));                                   \
            den[mi][i] += e;                                               \
            num[mi][i] = fmaf(e, d, num[mi][i]);                           \
        }                                                                  \
    } while (0)

    STAGE(0, 0);
    __syncthreads();

    // One barrier per K=64 step (frozen r9 structure).
#pragma unroll 1
    for (int w = 0; w < 16; ++w) {
        const int t0 = 2 * w;
        STAGE(1, t0 + 1);
        COMP_EPI(0);
        __syncthreads();
        if (t0 + 2 < 32) STAGE(0, t0 + 2);
        COMP_EPI(1);
        __syncthreads();
    }

    // Final epilogue. C/D 32x32: col = lane&31, row = (i&3)+8*(i>>2)+4*(lane>>5)
#pragma unroll
    for (int mi = 0; mi < 2; ++mi)
#pragma unroll
        for (int i = 0; i < 16; ++i) {
            float gg   = (num[mi][i] / den[mi][i]) * LN2;
            float gate = gg / (1.0f + __expf(-gg));
            float val  = gate * lin[mi][i];
            int r = row0 + wm * 64 + mi * 32 + (i & 3) + 8 * (i >> 2) + 4 * (lane >> 5);
            int c = col0 + wn * 32 + (lane & 31);
            O[(size_t)r * H_DIM + c] = val;
        }
#undef STAGE
#undef COMP_EPI
}

// ------------------------------------------------- fallback (round-1 path) --
#define MFMA16(A, B, C) __builtin_amdgcn_mfma_f32_16x16x32_bf16(A, B, C, 0, 0, 0)

__global__ __launch_bounds__(512) void dend_fused_v0(
    const float* __restrict__ X, const float* __restrict__ T,
    const float* __restrict__ W, float* __restrict__ O)
{
    __shared__ __align__(16) short lds[2][5][128 * 32];

    const int tid  = threadIdx.x;
    const int lane = tid & 63;
    const int wv   = tid >> 6;
    const int wm   = wv >> 2;
    const int wn   = wv & 3;

    const int bid     = blockIdx.x;
    const int logical = (bid & 7) * 32 + (bid >> 3);
    const int hb   = logical >> 5;
    const int nb   = logical & 31;
    const int row0 = nb * 128;
    const int col0 = hb * 128;

    const int srow  = tid >> 2;
    const int schn  = tid & 3;
    const int sslot = schn ^ ((srow >> 1) & 3);
    const int swoff = srow * 32 + sslot * 8;

    const float* gx = X + (size_t)(row0 + srow) * K_DIM + schn * 8;
    const float* gw = W + (size_t)(col0 + srow) * K_DIM + schn * 8;
    const float* gt = T + (size_t)(col0 + srow) * K_DIM + schn * 8;

    const int g = lane >> 4;
    int a_off[4], b_off[2];
#pragma unroll
    for (int mi = 0; mi < 4; ++mi) {
        int r = wm * 64 + mi * 16 + (lane & 15);
        a_off[mi] = r * 32 + (g ^ ((r >> 1) & 3)) * 8;
    }
#pragma unroll
    for (int nj = 0; nj < 2; ++nj) {
        int r = wn * 32 + nj * 16 + (lane & 15);
        b_off[nj] = r * 32 + (g ^ ((r >> 1) & 3)) * 8;
    }

    const f32x4 zeroc = (f32x4)0.0f;
    f32x4 lin[4][2], num[4][2], den[4][2], win[4][2];
#pragma unroll
    for (int mi = 0; mi < 4; ++mi)
#pragma unroll
        for (int nj = 0; nj < 2; ++nj) {
            lin[mi][nj] = zeroc; num[mi][nj] = zeroc; den[mi][nj] = zeroc;
        }

    f32x4 rx0, rx1, rw0, rw1, rt0, rt1;

#define LOADS(t) do {                                                   \
        const float* px = gx + (size_t)(t) * 32;                        \
        const float* pw = gw + (size_t)(t) * 32;                        \
        const float* pt = gt + (size_t)(t) * 32;                        \
        rx0 = *(const f32x4*)(px); rx1 = *(const f32x4*)(px + 4);       \
        rw0 = *(const f32x4*)(pw); rw1 = *(const f32x4*)(pw + 4);       \
        rt0 = *(const f32x4*)(pt); rt1 = *(const f32x4*)(pt + 4);       \
    } while (0)

#define WRITE(buf) do {                                                 \
        short8 vh, vl;                                                  \
        cvt_split(rx0, rx1, vh, vl);                                    \
        *(short8*)&lds[buf][0][swoff] = vh;                             \
        *(short8*)&lds[buf][1][swoff] = vl;                             \
        cvt_split(rw0, rw1, vh, vl);                                    \
        *(short8*)&lds[buf][2][swoff] = vh;                             \
        *(short8*)&lds[buf][3][swoff] = vl;                             \
        *(short8*)&lds[buf][4][swoff] = cvt_hi(rt0, rt1);               \
    } while (0)

#define COMPUTE(buf, ZW) do {                                           \
        short8 bwh[2], bwl[2], bth[2];                                  \
        _Pragma("unroll")                                               \
        for (int nj = 0; nj < 2; ++nj) {                                \
            bwh[nj] = *(const short8*)&lds[buf][2][b_off[nj]];          \
            bwl[nj] = *(const short8*)&lds[buf][3][b_off[nj]];          \
            bth[nj] = *(const short8*)&lds[buf][4][b_off[nj]];          \
        }                                                               \
        _Pragma("unroll")                                               \
        for (int mi = 0; mi < 4; ++mi) {                                \
            short8 ah = *(const short8*)&lds[buf][0][a_off[mi]];        \
            short8 al = *(const short8*)&lds[buf][1][a_off[mi]];        \
            _Pragma("unroll")                                           \
            for (int nj = 0; nj < 2; ++nj) {                            \
                lin[mi][nj] = MFMA16(ah, bwh[nj], lin[mi][nj]);         \
                lin[mi][nj] = MFMA16(al, bwh[nj], lin[mi][nj]);         \
                lin[mi][nj] = MFMA16(ah, bwl[nj], lin[mi][nj]);         \
                win[mi][nj] = MFMA16(ah, bth[nj], (ZW) ? zeroc : win[mi][nj]); \
            }                                                           \
        }                                                               \
    } while (0)

#define EPILOG() do {                                                   \
        _Pragma("unroll")                                               \
        for (int mi = 0; mi < 4; ++mi)                                  \
        _Pragma("unroll")                                               \
        for (int nj = 0; nj < 2; ++nj)                                  \
        _Pragma("unroll")                                               \
        for (int i = 0; i < 4; ++i) {                                   \
            float d = win[mi][nj][i];                                   \
            float e = __expf(fabsf(d));                                 \
            den[mi][nj][i] += e;                                        \
            num[mi][nj][i] = fmaf(e, d, num[mi][nj][i]);                \
        }                                                               \
    } while (0)

    LOADS(0);
    WRITE(0);
    __syncthreads();

#pragma unroll 1
    for (int w = 0; w < 32; ++w) {
        const int t0 = 2 * w;
        LOADS(t0 + 1);
        COMPUTE(0, true);
        __syncthreads();
        WRITE(1);
        __syncthreads();
        const bool more = (w < 31);
        if (more) LOADS(t0 + 2);
        COMPUTE(1, false);
        EPILOG();
        __syncthreads();
        if (more) WRITE(0);
        __syncthreads();
    }

#pragma unroll
    for (int mi = 0; mi < 4; ++mi)
#pragma unroll
        for (int nj = 0; nj < 2; ++nj)
#pragma unroll
            for (int i = 0; i < 4; ++i) {
                float gg   = num[mi][nj][i] / den[mi][nj][i];
                float gate = gg / (1.0f + __expf(-gg));
                float val  = gate * lin[mi][nj][i];
                int r = row0 + wm * 64 + mi * 16 + (lane >> 4) * 4 + i;
                int c = col0 + wn * 32 + nj * 16 + (lane & 15);
                O[(size_t)r * H_DIM + c] = val;
            }
#undef LOADS
#undef WRITE
#undef COMPUTE
#undef EPILOG
}

extern "C" void kernel_launch(void* const* d_in, const int* in_sizes, int n_in,
                              void* d_out, int out_size, void* d_ws, size_t ws_size,
                              hipStream_t stream) {
    const float* X = (const float*)d_in[0];   // x [4096,2048]
    const float* T = (const float*)d_in[1];   // template_flat [1024,2048]
    const float* W = (const float*)d_in[2];   // weights [1024,2048]
    float* O = (float*)d_out;                 // [4096,1024]
    (void)in_sizes; (void)n_in; (void)out_size;

    if (ws_size >= WS_NEED) {
        unsigned short* XHp = (unsigned short*)d_ws;
        unsigned short* XLp = XHp + X_ELEMS;
        unsigned short* WHp = XLp + X_ELEMS;
        unsigned short* WLp = WHp + W_ELEMS;
        unsigned short* THp = WLp + W_ELEMS;
        prepass_all<<<XB + 2 * WB, 256, 0, stream>>>(X, W, T, XHp, XLp, WHp, WLp, THp);
        dend_gemm<<<256, 512, 0, stream>>>(XHp, XLp, WHp, WLp, THp, O);
    } else {
        dend_fused_v0<<<256, 512, 0, stream>>>(X, T, W, O);
    }
}